// Round 1
// baseline (2042.651 us; speedup 1.0000x reference)
//
#include <hip/hip_runtime.h>
#include <math.h>

#define B_TOT   65536
#define N_DIM   64
#define K_MIX   8
#define H_DIM   1024
#define O2      1024          // 2*K*N
#define ROWS    16
#define NBLK    (B_TOT / ROWS)   // 4096
#define LOG2PI_F 1.8378770664093453f
#define HALF_N_LOG2PI (0.5f * 64.0f * LOG2PI_F)
#define LOG_1EM8 (-18.420680743952367f)

__device__ __forceinline__ float eluf(float v) {
    return v > 0.0f ? v : expm1f(v);
}

// one MDN nll summand: d^2/var + log(var), var = max(exp(vr), 1e-8)
__device__ __forceinline__ float nll_term(float yv, float mu, float vr) {
    float d = yv - mu;
    if (vr >= LOG_1EM8) {
        return fmaf(d * d, expf(-vr), vr);
    } else {
        return fmaf(d * d, 1e8f, LOG_1EM8);
    }
}

__global__ __launch_bounds__(256, 2)
void fused_mdn(const float* __restrict__ x, const float* __restrict__ y,
               const float* __restrict__ W1, const float* __restrict__ b1,
               const float* __restrict__ W2, const float* __restrict__ b2,
               const float* __restrict__ Wp1, const float* __restrict__ bp1,
               const float* __restrict__ Wp2, const float* __restrict__ bp2,
               float* __restrict__ partials)
{
    __shared__ float hs[ROWS * O2];        // 64 KB: h, then overwritten with fhatx
    __shared__ float scA[ROWS * N_DIM];    // 4 KB: x rows -> y rows -> pi-x rows
    __shared__ float scB[ROWS * N_DIM];    // 4 KB: pi hidden
    __shared__ float lps[ROWS * K_MIX];    // 512 B: lp[r_local][j]
    __shared__ float lses[ROWS];

    const int t = threadIdx.x;
    const int q = blockIdx.x;

    float4* hs4  = (float4*)hs;
    float4* scA4 = (float4*)scA;

    // ---------------- load x rows [16q, 16q+16) ----------------
    {
        const float4* x4 = (const float4*)x;
        scA4[t] = x4[q * 256 + t];
    }
    __syncthreads();

    float acc[ROWS][4];

    // ---------------- phase 1: h = elu(x @ W1 + b1), this thread owns cols 4t..4t+3
    {
        const float4* W1_4 = (const float4*)W1;
        const float4* b1_4 = (const float4*)b1;
        float4 bv = b1_4[t];
        #pragma unroll
        for (int r = 0; r < ROWS; ++r) {
            acc[r][0] = bv.x; acc[r][1] = bv.y; acc[r][2] = bv.z; acc[r][3] = bv.w;
        }
        for (int n4 = 0; n4 < N_DIM / 4; ++n4) {
            float4 w0 = W1_4[(n4 * 4 + 0) * 256 + t];
            float4 w1 = W1_4[(n4 * 4 + 1) * 256 + t];
            float4 w2 = W1_4[(n4 * 4 + 2) * 256 + t];
            float4 w3 = W1_4[(n4 * 4 + 3) * 256 + t];
            #pragma unroll
            for (int r = 0; r < ROWS; ++r) {
                float4 hv = scA4[r * 16 + n4];
                acc[r][0] += hv.x * w0.x + hv.y * w1.x + hv.z * w2.x + hv.w * w3.x;
                acc[r][1] += hv.x * w0.y + hv.y * w1.y + hv.z * w2.y + hv.w * w3.y;
                acc[r][2] += hv.x * w0.z + hv.y * w1.z + hv.z * w2.z + hv.w * w3.z;
                acc[r][3] += hv.x * w0.w + hv.y * w1.w + hv.z * w2.w + hv.w * w3.w;
            }
        }
        #pragma unroll
        for (int r = 0; r < ROWS; ++r) {
            float4 e;
            e.x = eluf(acc[r][0]); e.y = eluf(acc[r][1]);
            e.z = eluf(acc[r][2]); e.w = eluf(acc[r][3]);
            hs4[r * 256 + t] = e;
        }
    }
    __syncthreads();

    // ---------------- phase 2: fhatx = h @ W2 + b2 ----------------
    {
        const float4* W2_4 = (const float4*)W2;
        const float4* b2_4 = (const float4*)b2;
        float4 bv = b2_4[t];
        #pragma unroll
        for (int r = 0; r < ROWS; ++r) {
            acc[r][0] = bv.x; acc[r][1] = bv.y; acc[r][2] = bv.z; acc[r][3] = bv.w;
        }
        for (int k4 = 0; k4 < H_DIM / 4; ++k4) {
            float4 w0 = W2_4[(k4 * 4 + 0) * 256 + t];
            float4 w1 = W2_4[(k4 * 4 + 1) * 256 + t];
            float4 w2 = W2_4[(k4 * 4 + 2) * 256 + t];
            float4 w3 = W2_4[(k4 * 4 + 3) * 256 + t];
            #pragma unroll
            for (int r = 0; r < ROWS; ++r) {
                float4 hv = hs4[r * 256 + k4];
                acc[r][0] += hv.x * w0.x + hv.y * w1.x + hv.z * w2.x + hv.w * w3.x;
                acc[r][1] += hv.x * w0.y + hv.y * w1.y + hv.z * w2.y + hv.w * w3.y;
                acc[r][2] += hv.x * w0.z + hv.y * w1.z + hv.z * w2.z + hv.w * w3.z;
                acc[r][3] += hv.x * w0.w + hv.y * w1.w + hv.z * w2.w + hv.w * w3.w;
            }
        }
    }
    __syncthreads();   // everyone done reading h
    #pragma unroll
    for (int r = 0; r < ROWS; ++r) {
        float4 f; f.x = acc[r][0]; f.y = acc[r][1]; f.z = acc[r][2]; f.w = acc[r][3];
        hs4[r * 256 + t] = f;     // hs now holds fhatx
    }
    // ---------------- load y rows for the 16 outputs this block owns ----------------
    {   // output o = g_local*8 + j  ->  b' = 2q + (o>>3) + (o&7)*8192
        const float4* y4 = (const float4*)y;
        int o = t >> 4, c = t & 15;
        int bprime = 2 * q + (o >> 3) + (o & 7) * 8192;
        __syncthreads();          // fhatx writes + previous scA readers done
        scA4[o * 16 + c] = y4[bprime * 16 + c];
    }
    __syncthreads();

    // ---------------- phase 3: lp[r_l][j] ----------------
    if (t < 128) {
        int r_l = t >> 3, j = t & 7;
        int o = ((r_l >> 3) << 3) + j;     // y-row slot for this lp
        float sum = 0.0f;
        for (int i = 0; i < 16; ++i) {
            int ch = (i + t) & 15;         // rotate to spread LDS banks
            float4 mu4 = hs4[r_l * 256 + j * 16 + ch];
            float4 vr4 = hs4[r_l * 256 + 128 + j * 16 + ch];
            float4 yv4 = scA4[o * 16 + ch];
            sum += nll_term(yv4.x, mu4.x, vr4.x);
            sum += nll_term(yv4.y, mu4.y, vr4.y);
            sum += nll_term(yv4.z, mu4.z, vr4.z);
            sum += nll_term(yv4.w, mu4.w, vr4.w);
        }
        lps[t] = -0.5f * sum - HALF_N_LOG2PI;
    }
    __syncthreads();

    // ---------------- phase 4: pi network for the 16 outputs ----------------
    {   // load pi-x rows (x[b'], different rows than phase 1!)
        const float4* x4 = (const float4*)x;
        int o = t >> 4, c = t & 15;
        int bprime = 2 * q + (o >> 3) + (o & 7) * 8192;
        scA4[o * 16 + c] = x4[bprime * 16 + c];
    }
    __syncthreads();
    {   // tpi = elu(xp @ Wp1 + bp1): thread t -> col c = t&63, rows ob+4i
        int c = t & 63;
        int ob = t >> 6;
        float a[4];
        #pragma unroll
        for (int i = 0; i < 4; ++i) a[i] = bp1[c];
        for (int n = 0; n < 64; ++n) {
            float w = Wp1[n * 64 + c];
            #pragma unroll
            for (int i = 0; i < 4; ++i) a[i] += scA[(ob + 4 * i) * 64 + n] * w;
        }
        #pragma unroll
        for (int i = 0; i < 4; ++i) scB[(ob + 4 * i) * 64 + c] = eluf(a[i]);
    }
    __syncthreads();
    {   // logits, log-softmax over k (8 lanes), + lp, logsumexp over k
        if (t < 128) {
            int o = t >> 3, k = t & 7;
            float a = bp2[k];
            for (int n = 0; n < 64; ++n) a += scB[o * 64 + n] * Wp2[n * 8 + k];
            float m = a;
            m = fmaxf(m, __shfl_xor(m, 1));
            m = fmaxf(m, __shfl_xor(m, 2));
            m = fmaxf(m, __shfl_xor(m, 4));
            float e = expf(a - m);
            float s = e;
            s += __shfl_xor(s, 1); s += __shfl_xor(s, 2); s += __shfl_xor(s, 4);
            float logpi = a - m - logf(s);
            // lp index: r_l = 8*(o>>3) + k, j = o&7
            float v = logpi + lps[((o >> 3) * 8 + k) * 8 + (o & 7)];
            float mv = v;
            mv = fmaxf(mv, __shfl_xor(mv, 1));
            mv = fmaxf(mv, __shfl_xor(mv, 2));
            mv = fmaxf(mv, __shfl_xor(mv, 4));
            float ee = expf(v - mv);
            float ss = ee;
            ss += __shfl_xor(ss, 1); ss += __shfl_xor(ss, 2); ss += __shfl_xor(ss, 4);
            if (k == 0) lses[o] = mv + logf(ss);
        }
    }
    __syncthreads();
    if (t == 0) {
        float p = 0.0f;                 // deterministic serial sum of 16
        #pragma unroll
        for (int o = 0; o < ROWS; ++o) p += lses[o];
        partials[q] = p;
    }
}

__global__ void reduce_partials(const float* __restrict__ partials, float* __restrict__ out)
{
    __shared__ double red[256];
    int t = threadIdx.x;
    double s = 0.0;
    for (int i = t; i < NBLK; i += 256) s += (double)partials[i];
    red[t] = s;
    __syncthreads();
    for (int w = 128; w > 0; w >>= 1) {
        if (t < w) red[t] += red[t + w];
        __syncthreads();
    }
    if (t == 0) out[0] = (float)(-red[0] / (double)B_TOT);
}

extern "C" void kernel_launch(void* const* d_in, const int* in_sizes, int n_in,
                              void* d_out, int out_size, void* d_ws, size_t ws_size,
                              hipStream_t stream)
{
    const float* x   = (const float*)d_in[0];
    const float* y   = (const float*)d_in[1];
    const float* W1  = (const float*)d_in[2];
    const float* b1  = (const float*)d_in[3];
    const float* W2  = (const float*)d_in[4];
    const float* b2  = (const float*)d_in[5];
    const float* Wp1 = (const float*)d_in[6];
    const float* bp1 = (const float*)d_in[7];
    const float* Wp2 = (const float*)d_in[8];
    const float* bp2 = (const float*)d_in[9];
    float* partials = (float*)d_ws;    // NBLK floats = 16 KB

    fused_mdn<<<NBLK, 256, 0, stream>>>(x, y, W1, b1, W2, b2,
                                        Wp1, bp1, Wp2, bp2, partials);
    reduce_partials<<<1, 256, 0, stream>>>(partials, (float*)d_out);
}

// Round 2
// 1181.244 us; speedup vs baseline: 1.7292x; 1.7292x over previous
//
#include <hip/hip_runtime.h>
#include <math.h>

typedef __attribute__((ext_vector_type(8))) short short8;
typedef __attribute__((ext_vector_type(4))) float f32x4;

#define B_TOT   65536
#define ROWS    32
#define NBLK    (B_TOT / ROWS)      // 2048
#define THREADS 512
#define LOG2PI_F 1.8378770664093453f
#define HALF_N_LOG2PI (0.5f * 64.0f * LOG2PI_F)
#define LOG_1EM8 (-18.420680743952367f)

// ws layout (bytes)
#define WS_W2HI 0
#define WS_W2LO (2*1024*1024)
#define WS_W1HI (4*1024*1024)
#define WS_W1LO (WS_W1HI + 128*1024)
#define WS_PART (WS_W1LO + 128*1024)

__device__ __forceinline__ void split_bf16(float a, unsigned short& hi, unsigned short& lo) {
    unsigned u = __float_as_uint(a);
    unsigned r = u + 0x7FFFu + ((u >> 16) & 1u);
    hi = (unsigned short)(r >> 16);
    float fhi = __uint_as_float(((unsigned)hi) << 16);
    float fl = a - fhi;
    unsigned v = __float_as_uint(fl);
    unsigned s = v + 0x7FFFu + ((v >> 16) & 1u);
    lo = (unsigned short)(s >> 16);
}

__device__ __forceinline__ float eluf(float v) {
    return v > 0.0f ? v : expm1f(v);
}

__device__ __forceinline__ float nll_term(float yv, float mu, float vr) {
    float d = yv - mu;
    if (vr >= LOG_1EM8) return fmaf(d * d, expf(-vr), vr);
    return fmaf(d * d, 1e8f, LOG_1EM8);
}

// src fp32 [Kd][1024] -> dHi/dLo bf16 [1024][Kd] (transposed, split)
__global__ __launch_bounds__(256)
void transpose_split(const float* __restrict__ src, unsigned short* __restrict__ dHi,
                     unsigned short* __restrict__ dLo, int Kd)
{
    __shared__ float ts[64][65];
    const int t = threadIdx.x;
    const int k0 = blockIdx.x * 64, n0 = blockIdx.y * 64;
    {
        int r = t >> 2, c4 = t & 3;
        for (int i = 0; i < 4; ++i) {
            int cc = i * 4 + c4;
            float4 v = *(const float4*)&src[(size_t)(k0 + r) * 1024 + n0 + cc * 4];
            ts[r][cc*4+0] = v.x; ts[r][cc*4+1] = v.y;
            ts[r][cc*4+2] = v.z; ts[r][cc*4+3] = v.w;
        }
    }
    __syncthreads();
    {
        int n = t >> 2;
        for (int i = 0; i < 4; ++i) {
            int kk = (i * 4 + (t & 3)) * 4;
            ushort4 h, l;
            split_bf16(ts[kk+0][n], h.x, l.x);
            split_bf16(ts[kk+1][n], h.y, l.y);
            split_bf16(ts[kk+2][n], h.z, l.z);
            split_bf16(ts[kk+3][n], h.w, l.w);
            *(ushort4*)&dHi[(size_t)(n0 + n) * Kd + k0 + kk] = h;
            *(ushort4*)&dLo[(size_t)(n0 + n) * Kd + k0 + kk] = l;
        }
    }
}

__global__ __launch_bounds__(THREADS, 2)
void fused_mdn(const float* __restrict__ x, const float* __restrict__ y,
               const unsigned short* __restrict__ W1hiT, const unsigned short* __restrict__ W1loT,
               const float* __restrict__ b1,
               const unsigned short* __restrict__ W2hiT, const unsigned short* __restrict__ W2loT,
               const float* __restrict__ b2,
               const float* __restrict__ Wp1, const float* __restrict__ bp1,
               const float* __restrict__ Wp2, const float* __restrict__ bp2,
               float* __restrict__ partials)
{
    __shared__ __align__(16) unsigned short hsu[2][ROWS * 1024]; // 128 KB: h hi/lo, then fhatx fp32
    __shared__ __align__(16) float scAB[4096];                   // 16 KB: xs hi/lo, then pi scratch
    __shared__ float lps[256];
    __shared__ float lses[ROWS];

    const int t   = threadIdx.x;
    const int q   = blockIdx.x;
    const int w   = t >> 6;
    const int l   = t & 63;
    const int g   = l >> 4;
    const int l15 = l & 15;

    unsigned short* xs_hi = (unsigned short*)scAB;   // 2048 ushorts (4 KB)
    unsigned short* xs_lo = xs_hi + 2048;

    // ---------- phase 0: stage x rows [32q,32q+32), split hi/lo, swizzled ----------
    {
        const float4* x4 = (const float4*)x;
        int r = t >> 4, c = t & 15;
        float4 v = x4[(size_t)(q * ROWS + r) * 16 + c];
        float vv[4] = {v.x, v.y, v.z, v.w};
        #pragma unroll
        for (int i = 0; i < 4; ++i) {
            int col = c * 4 + i;
            unsigned short hi, lo;
            split_bf16(vv[i], hi, lo);
            int idx = r * 64 + (col ^ ((r & 7) << 3));
            xs_hi[idx] = hi; xs_lo[idx] = lo;
        }
    }
    __syncthreads();

    f32x4 acc[2][8];

    // ---------- phase 1: h = elu(x @ W1 + b1) via split-bf16 MFMA ----------
    #pragma unroll
    for (int ct = 0; ct < 8; ++ct) {
        float bv = b1[w * 128 + ct * 16 + l15];
        acc[0][ct] = (f32x4){bv, bv, bv, bv};
        acc[1][ct] = (f32x4){bv, bv, bv, bv};
    }
    #pragma unroll
    for (int k0 = 0; k0 < 64; k0 += 32) {
        short8 aH[2], aL[2];
        #pragma unroll
        for (int rt = 0; rt < 2; ++rt) {
            int row = rt * 16 + l15;
            int cidx = row * 64 + ((k0 + 8 * g) ^ ((row & 7) << 3));
            aH[rt] = *(const short8*)&xs_hi[cidx];
            aL[rt] = *(const short8*)&xs_lo[cidx];
        }
        #pragma unroll
        for (int ct = 0; ct < 8; ++ct) {
            int n = w * 128 + ct * 16 + l15;
            size_t bidx = (size_t)n * 64 + k0 + 8 * g;
            short8 bH = *(const short8*)&W1hiT[bidx];
            short8 bL = *(const short8*)&W1loT[bidx];
            #pragma unroll
            for (int rt = 0; rt < 2; ++rt) {
                acc[rt][ct] = __builtin_amdgcn_mfma_f32_16x16x32_bf16(aH[rt], bH, acc[rt][ct], 0, 0, 0);
                acc[rt][ct] = __builtin_amdgcn_mfma_f32_16x16x32_bf16(aH[rt], bL, acc[rt][ct], 0, 0, 0);
                acc[rt][ct] = __builtin_amdgcn_mfma_f32_16x16x32_bf16(aL[rt], bH, acc[rt][ct], 0, 0, 0);
            }
        }
    }
    // epilogue: ELU, split, write h hi/lo into hsu (swizzled)
    #pragma unroll
    for (int rt = 0; rt < 2; ++rt)
        #pragma unroll
        for (int ct = 0; ct < 8; ++ct)
            #pragma unroll
            for (int rg = 0; rg < 4; ++rg) {
                float v = eluf(acc[rt][ct][rg]);
                int row = rt * 16 + 4 * g + rg;
                int col = w * 128 + ct * 16 + l15;
                unsigned short hi, lo;
                split_bf16(v, hi, lo);
                int idx = row * 1024 + (col ^ ((row & 7) << 3));
                hsu[0][idx] = hi; hsu[1][idx] = lo;
            }
    __syncthreads();

    // ---------- phase 2: fhatx = h @ W2 + b2 via split-bf16 MFMA ----------
    #pragma unroll
    for (int ct = 0; ct < 8; ++ct) {
        float bv = b2[w * 128 + ct * 16 + l15];
        acc[0][ct] = (f32x4){bv, bv, bv, bv};
        acc[1][ct] = (f32x4){bv, bv, bv, bv};
    }
    const unsigned short* hhi = hsu[0];
    const unsigned short* hlo = hsu[1];
    for (int k0 = 0; k0 < 1024; k0 += 32) {
        short8 aH[2], aL[2];
        #pragma unroll
        for (int rt = 0; rt < 2; ++rt) {
            int row = rt * 16 + l15;
            int cidx = row * 1024 + ((k0 + 8 * g) ^ ((row & 7) << 3));
            aH[rt] = *(const short8*)&hhi[cidx];
            aL[rt] = *(const short8*)&hlo[cidx];
        }
        #pragma unroll
        for (int ct = 0; ct < 8; ++ct) {
            int n = w * 128 + ct * 16 + l15;
            size_t bidx = (size_t)n * 1024 + k0 + 8 * g;
            short8 bH = *(const short8*)&W2hiT[bidx];
            short8 bL = *(const short8*)&W2loT[bidx];
            #pragma unroll
            for (int rt = 0; rt < 2; ++rt) {
                acc[rt][ct] = __builtin_amdgcn_mfma_f32_16x16x32_bf16(aH[rt], bH, acc[rt][ct], 0, 0, 0);
                acc[rt][ct] = __builtin_amdgcn_mfma_f32_16x16x32_bf16(aH[rt], bL, acc[rt][ct], 0, 0, 0);
                acc[rt][ct] = __builtin_amdgcn_mfma_f32_16x16x32_bf16(aL[rt], bH, acc[rt][ct], 0, 0, 0);
            }
        }
    }
    __syncthreads();   // all h reads done
    // write fhatx fp32 into hsu region (swizzled by (row>>2)&3)
    float* fx = (float*)hsu;
    #pragma unroll
    for (int rt = 0; rt < 2; ++rt)
        #pragma unroll
        for (int ct = 0; ct < 8; ++ct)
            #pragma unroll
            for (int rg = 0; rg < 4; ++rg) {
                int row = rt * 16 + 4 * g + rg;
                int col = w * 128 + ct * 16 + l15;
                fx[row * 1024 + (col ^ (((row >> 2) & 3) << 4))] = acc[rt][ct][rg];
            }
    __syncthreads();

    // ---------- phase 3: lp[o][k'] (256 tasks) + phase-4 xp staging ----------
    if (t < 256) {
        int o = t >> 3, kp = t & 7;
        int gg = o >> 3, j = o & 7;
        int r_l = 8 * gg + kp;
        int bprime = 4 * q + gg + j * 8192;
        int s = (r_l >> 2) & 3;
        const float4* y4 = (const float4*)y;
        float sum = 0.0f;
        for (int i = 0; i < 16; ++i) {
            int ch = (i + 2 * kp + j) & 15;
            float4 mu4 = *(const float4*)&fx[r_l * 1024 + ((j * 64 + ch * 4) ^ (s << 4))];
            float4 vr4 = *(const float4*)&fx[r_l * 1024 + ((512 + j * 64 + ch * 4) ^ (s << 4))];
            float4 yv4 = y4[(size_t)bprime * 16 + ch];
            sum += nll_term(yv4.x, mu4.x, vr4.x);
            sum += nll_term(yv4.y, mu4.y, vr4.y);
            sum += nll_term(yv4.z, mu4.z, vr4.z);
            sum += nll_term(yv4.w, mu4.w, vr4.w);
        }
        lps[t] = -0.5f * sum - HALF_N_LOG2PI;
    }
    {   // stage xp rows (32 outputs) into scA
        const float4* x4 = (const float4*)x;
        int o = t >> 4, c = t & 15;
        int bprime = 4 * q + (o >> 3) + (o & 7) * 8192;
        float4* scA4 = (float4*)scAB;
        scA4[o * 16 + c] = x4[(size_t)bprime * 16 + c];
    }
    __syncthreads();

    // ---------- phase 4: pi network ----------
    float* scA = scAB;          // [32][64] xp
    float* scB = scAB + 2048;   // [32][64] tpi
    {
        int c = t & 63, ob = t >> 6;
        float a[4];
        #pragma unroll
        for (int i = 0; i < 4; ++i) a[i] = bp1[c];
        for (int n = 0; n < 64; ++n) {
            float wv = Wp1[n * 64 + c];
            #pragma unroll
            for (int i = 0; i < 4; ++i) a[i] += scA[(ob + 8 * i) * 64 + n] * wv;
        }
        #pragma unroll
        for (int i = 0; i < 4; ++i) scB[(ob + 8 * i) * 64 + c] = eluf(a[i]);
    }
    __syncthreads();
    if (t < 256) {
        int o = t >> 3, k = t & 7;
        float a = bp2[k];
        for (int n = 0; n < 64; ++n) a += scB[o * 64 + n] * Wp2[n * 8 + k];
        float m = a;
        m = fmaxf(m, __shfl_xor(m, 1));
        m = fmaxf(m, __shfl_xor(m, 2));
        m = fmaxf(m, __shfl_xor(m, 4));
        float e = expf(a - m);
        float sden = e;
        sden += __shfl_xor(sden, 1); sden += __shfl_xor(sden, 2); sden += __shfl_xor(sden, 4);
        float logpi = a - m - logf(sden);
        float v = logpi + lps[o * 8 + k];
        float mv = v;
        mv = fmaxf(mv, __shfl_xor(mv, 1));
        mv = fmaxf(mv, __shfl_xor(mv, 2));
        mv = fmaxf(mv, __shfl_xor(mv, 4));
        float ee = expf(v - mv);
        float ss = ee;
        ss += __shfl_xor(ss, 1); ss += __shfl_xor(ss, 2); ss += __shfl_xor(ss, 4);
        if (k == 0) lses[o] = mv + logf(ss);
    }
    __syncthreads();
    if (t == 0) {
        float p = 0.0f;
        #pragma unroll
        for (int o = 0; o < ROWS; ++o) p += lses[o];
        partials[q] = p;
    }
}

__global__ void reduce_partials(const float* __restrict__ partials, float* __restrict__ out)
{
    __shared__ double red[256];
    int t = threadIdx.x;
    double s = 0.0;
    for (int i = t; i < NBLK; i += 256) s += (double)partials[i];
    red[t] = s;
    __syncthreads();
    for (int w = 128; w > 0; w >>= 1) {
        if (t < w) red[t] += red[t + w];
        __syncthreads();
    }
    if (t == 0) out[0] = (float)(-red[0] / (double)B_TOT);
}

extern "C" void kernel_launch(void* const* d_in, const int* in_sizes, int n_in,
                              void* d_out, int out_size, void* d_ws, size_t ws_size,
                              hipStream_t stream)
{
    const float* x   = (const float*)d_in[0];
    const float* y   = (const float*)d_in[1];
    const float* W1  = (const float*)d_in[2];
    const float* b1  = (const float*)d_in[3];
    const float* W2  = (const float*)d_in[4];
    const float* b2  = (const float*)d_in[5];
    const float* Wp1 = (const float*)d_in[6];
    const float* bp1 = (const float*)d_in[7];
    const float* Wp2 = (const float*)d_in[8];
    const float* bp2 = (const float*)d_in[9];

    char* ws = (char*)d_ws;
    unsigned short* W2hiT = (unsigned short*)(ws + WS_W2HI);
    unsigned short* W2loT = (unsigned short*)(ws + WS_W2LO);
    unsigned short* W1hiT = (unsigned short*)(ws + WS_W1HI);
    unsigned short* W1loT = (unsigned short*)(ws + WS_W1LO);
    float* partials       = (float*)(ws + WS_PART);

    transpose_split<<<dim3(16, 16), 256, 0, stream>>>(W2, W2hiT, W2loT, 1024);
    transpose_split<<<dim3(1, 16), 256, 0, stream>>>(W1, W1hiT, W1loT, 64);
    fused_mdn<<<NBLK, THREADS, 0, stream>>>(x, y, W1hiT, W1loT, b1, W2hiT, W2loT, b2,
                                            Wp1, bp1, Wp2, bp2, partials);
    reduce_partials<<<1, 256, 0, stream>>>(partials, (float*)d_out);
}

// Round 5
// 637.656 us; speedup vs baseline: 3.2034x; 1.8525x over previous
//
#include <hip/hip_runtime.h>
#include <math.h>

typedef __attribute__((ext_vector_type(8))) short short8;
typedef __attribute__((ext_vector_type(4))) float f32x4;

#define B_TOT   65536
#define ROWS    32
#define NBLK    (B_TOT / ROWS)      // 2048
#define THREADS 1024
#define LOG2PI_F 1.8378770664093453f
#define HALF_N_LOG2PI (0.5f * 64.0f * LOG2PI_F)
#define LOG_1EM8 (-18.420680743952367f)

// ws layout (bytes)
#define WS_W2HI 0
#define WS_W2LO (2*1024*1024)
#define WS_W1HI (4*1024*1024)
#define WS_W1LO (WS_W1HI + 128*1024)
#define WS_PART (WS_W1LO + 128*1024)

__device__ __forceinline__ void split_bf16(float a, unsigned short& hi, unsigned short& lo) {
    unsigned u = __float_as_uint(a);
    unsigned r = u + 0x7FFFu + ((u >> 16) & 1u);
    hi = (unsigned short)(r >> 16);
    float fhi = __uint_as_float(((unsigned)hi) << 16);
    float fl = a - fhi;
    unsigned v = __float_as_uint(fl);
    unsigned s = v + 0x7FFFu + ((v >> 16) & 1u);
    lo = (unsigned short)(s >> 16);
}

__device__ __forceinline__ float eluf(float v) {
    return v > 0.0f ? v : expm1f(v);
}

__device__ __forceinline__ float nll_term(float yv, float mu, float vr) {
    float d = yv - mu;
    if (vr >= LOG_1EM8) return fmaf(d * d, expf(-vr), vr);
    return fmaf(d * d, 1e8f, LOG_1EM8);
}

// src fp32 [Kd][1024] -> dHi/dLo bf16 packed [(Kd/32)][1024 n][32 k]
__global__ __launch_bounds__(256)
void pack_split(const float* __restrict__ src, unsigned short* __restrict__ dHi,
                unsigned short* __restrict__ dLo, int Kd)
{
    __shared__ float ts[64][65];
    const int t = threadIdx.x;
    const int k0 = blockIdx.x * 64, n0 = blockIdx.y * 64;
    {
        int r = t >> 2, c4 = t & 3;
        for (int i = 0; i < 4; ++i) {
            int cc = i * 4 + c4;
            float4 v = *(const float4*)&src[(size_t)(k0 + r) * 1024 + n0 + cc * 4];
            ts[r][cc*4+0] = v.x; ts[r][cc*4+1] = v.y;
            ts[r][cc*4+2] = v.z; ts[r][cc*4+3] = v.w;
        }
    }
    __syncthreads();
    {
        int n = t >> 2;
        for (int i = 0; i < 4; ++i) {
            int kk = (i * 4 + (t & 3)) * 4;      // 0..60, 4-aligned
            int k = k0 + kk;
            ushort4 h, l;
            split_bf16(ts[kk+0][n], h.x, l.x);
            split_bf16(ts[kk+1][n], h.y, l.y);
            split_bf16(ts[kk+2][n], h.z, l.z);
            split_bf16(ts[kk+3][n], h.w, l.w);
            size_t off = (size_t)(k >> 5) * 32768 + (size_t)(n0 + n) * 32 + (k & 31);
            *(ushort4*)&dHi[off] = h;
            *(ushort4*)&dLo[off] = l;
        }
    }
}

__global__ __launch_bounds__(THREADS, 4)
void fused_mdn(const float* __restrict__ x, const float* __restrict__ y,
               const unsigned short* __restrict__ W1P_hi, const unsigned short* __restrict__ W1P_lo,
               const float* __restrict__ b1,
               const unsigned short* __restrict__ W2P_hi, const unsigned short* __restrict__ W2P_lo,
               const float* __restrict__ b2,
               const float* __restrict__ Wp1, const float* __restrict__ bp1,
               const float* __restrict__ Wp2, const float* __restrict__ bp2,
               float* __restrict__ partials)
{
    __shared__ __align__(16) unsigned short hsu[2][ROWS * 1024]; // 128 KB: h hi/lo, then fhatx fp32
    __shared__ __align__(16) float scAB[4096];                   // 16 KB
    __shared__ float lps[256];
    __shared__ float lses[ROWS];

    const int t   = threadIdx.x;
    const int q   = blockIdx.x;
    const int w   = t >> 6;      // 0..15, wave owns cols [w*64, w*64+64)
    const int l   = t & 63;
    const int g   = l >> 4;
    const int l15 = l & 15;

    unsigned short* xs_hi = (unsigned short*)scAB;   // [32][64] swizzled
    unsigned short* xs_lo = xs_hi + 2048;

    // ---------- phase 0: stage x rows [32q,32q+32), split hi/lo, swizzled ----------
    if (t < 512) {
        const float4* x4 = (const float4*)x;
        int r = t >> 4, c = t & 15;
        float4 v = x4[(size_t)(q * ROWS + r) * 16 + c];
        float vv[4] = {v.x, v.y, v.z, v.w};
        #pragma unroll
        for (int i = 0; i < 4; ++i) {
            int col = c * 4 + i;
            unsigned short hi, lo;
            split_bf16(vv[i], hi, lo);
            int idx = r * 64 + (col ^ ((r & 7) << 3));
            xs_hi[idx] = hi; xs_lo[idx] = lo;
        }
    }
    __syncthreads();

    f32x4 acc[2][4];

    // ---------- phase 1: h = elu(x @ W1 + b1) ----------
    #pragma unroll
    for (int ct = 0; ct < 4; ++ct) {
        float bv = b1[w * 64 + ct * 16 + l15];
        acc[0][ct] = (f32x4){bv, bv, bv, bv};
        acc[1][ct] = (f32x4){bv, bv, bv, bv};
    }
    #pragma unroll
    for (int k0 = 0; k0 < 64; k0 += 32) {
        short8 bH[4], bL[4];
        #pragma unroll
        for (int ct = 0; ct < 4; ++ct) {
            int n = w * 64 + ct * 16 + l15;
            size_t off = (size_t)(k0 >> 5) * 32768 + (size_t)n * 32 + 8 * g;
            bH[ct] = *(const short8*)&W1P_hi[off];
            bL[ct] = *(const short8*)&W1P_lo[off];
        }
        short8 aH[2], aL[2];
        #pragma unroll
        for (int rt = 0; rt < 2; ++rt) {
            int row = rt * 16 + l15;
            int cidx = row * 64 + ((k0 + 8 * g) ^ ((row & 7) << 3));
            aH[rt] = *(const short8*)&xs_hi[cidx];
            aL[rt] = *(const short8*)&xs_lo[cidx];
        }
        #pragma unroll
        for (int ct = 0; ct < 4; ++ct)
            #pragma unroll
            for (int rt = 0; rt < 2; ++rt) {
                acc[rt][ct] = __builtin_amdgcn_mfma_f32_16x16x32_bf16(aH[rt], bH[ct], acc[rt][ct], 0, 0, 0);
                acc[rt][ct] = __builtin_amdgcn_mfma_f32_16x16x32_bf16(aH[rt], bL[ct], acc[rt][ct], 0, 0, 0);
                acc[rt][ct] = __builtin_amdgcn_mfma_f32_16x16x32_bf16(aL[rt], bH[ct], acc[rt][ct], 0, 0, 0);
            }
    }
    // epilogue: ELU, split, write h hi/lo into hsu (swizzled)
    #pragma unroll
    for (int rt = 0; rt < 2; ++rt)
        #pragma unroll
        for (int ct = 0; ct < 4; ++ct)
            #pragma unroll
            for (int rg = 0; rg < 4; ++rg) {
                float v = eluf(acc[rt][ct][rg]);
                int row = rt * 16 + 4 * g + rg;
                int col = w * 64 + ct * 16 + l15;
                unsigned short hi, lo;
                split_bf16(v, hi, lo);
                int idx = row * 1024 + (col ^ ((row & 7) << 3));
                hsu[0][idx] = hi; hsu[1][idx] = lo;
            }
    __syncthreads();

    // ---------- phase 2: fhatx = h @ W2 + b2 ----------
    #pragma unroll
    for (int ct = 0; ct < 4; ++ct) {
        float bv = b2[w * 64 + ct * 16 + l15];
        acc[0][ct] = (f32x4){bv, bv, bv, bv};
        acc[1][ct] = (f32x4){bv, bv, bv, bv};
    }
    const unsigned short* hhi = hsu[0];
    const unsigned short* hlo = hsu[1];
    #pragma unroll 2
    for (int k0 = 0; k0 < 1024; k0 += 32) {
        short8 bH[4], bL[4];
        #pragma unroll
        for (int ct = 0; ct < 4; ++ct) {
            int n = w * 64 + ct * 16 + l15;
            size_t off = (size_t)(k0 >> 5) * 32768 + (size_t)n * 32 + 8 * g;
            bH[ct] = *(const short8*)&W2P_hi[off];
            bL[ct] = *(const short8*)&W2P_lo[off];
        }
        short8 aH[2], aL[2];
        #pragma unroll
        for (int rt = 0; rt < 2; ++rt) {
            int row = rt * 16 + l15;
            int cidx = row * 1024 + ((k0 + 8 * g) ^ ((row & 7) << 3));
            aH[rt] = *(const short8*)&hhi[cidx];
            aL[rt] = *(const short8*)&hlo[cidx];
        }
        #pragma unroll
        for (int ct = 0; ct < 4; ++ct)
            #pragma unroll
            for (int rt = 0; rt < 2; ++rt) {
                acc[rt][ct] = __builtin_amdgcn_mfma_f32_16x16x32_bf16(aH[rt], bH[ct], acc[rt][ct], 0, 0, 0);
                acc[rt][ct] = __builtin_amdgcn_mfma_f32_16x16x32_bf16(aH[rt], bL[ct], acc[rt][ct], 0, 0, 0);
                acc[rt][ct] = __builtin_amdgcn_mfma_f32_16x16x32_bf16(aL[rt], bH[ct], acc[rt][ct], 0, 0, 0);
            }
    }
    __syncthreads();   // all h reads done
    // write fhatx fp32 into hsu region (swizzled)
    float* fx = (float*)hsu;
    #pragma unroll
    for (int rt = 0; rt < 2; ++rt)
        #pragma unroll
        for (int ct = 0; ct < 4; ++ct)
            #pragma unroll
            for (int rg = 0; rg < 4; ++rg) {
                int row = rt * 16 + 4 * g + rg;
                int col = w * 64 + ct * 16 + l15;
                fx[row * 1024 + (col ^ (((row >> 2) & 3) << 4))] = acc[rt][ct][rg];
            }
    __syncthreads();

    // ---------- phase 3: lp[o][k'] (256 tasks) + phase-4 xp staging ----------
    if (t < 256) {
        int o = t >> 3, kp = t & 7;
        int gg = o >> 3, j = o & 7;
        int r_l = 8 * gg + kp;
        int bprime = 4 * q + gg + j * 8192;
        int s = (r_l >> 2) & 3;
        const float4* y4 = (const float4*)y;
        float sum = 0.0f;
        for (int i = 0; i < 16; ++i) {
            int ch = (i + 2 * kp + j) & 15;
            float4 mu4 = *(const float4*)&fx[r_l * 1024 + ((j * 64 + ch * 4) ^ (s << 4))];
            float4 vr4 = *(const float4*)&fx[r_l * 1024 + ((512 + j * 64 + ch * 4) ^ (s << 4))];
            float4 yv4 = y4[(size_t)bprime * 16 + ch];
            sum += nll_term(yv4.x, mu4.x, vr4.x);
            sum += nll_term(yv4.y, mu4.y, vr4.y);
            sum += nll_term(yv4.z, mu4.z, vr4.z);
            sum += nll_term(yv4.w, mu4.w, vr4.w);
        }
        lps[t] = -0.5f * sum - HALF_N_LOG2PI;
    } else if (t >= 512) {   // stage xp rows (32 outputs) into scA
        const float4* x4 = (const float4*)x;
        int t2 = t - 512;
        int o = t2 >> 4, c = t2 & 15;
        int bprime = 4 * q + (o >> 3) + (o & 7) * 8192;
        float4* scA4 = (float4*)scAB;
        scA4[o * 16 + c] = x4[(size_t)bprime * 16 + c];
    }
    __syncthreads();

    // ---------- phase 4: pi network ----------
    float* scA = scAB;          // [32][64] xp
    float* scB = scAB + 2048;   // [32][64] tpi
    {
        int c = t & 63, ob = t >> 6;   // ob 0..15, rows {ob, ob+16}
        float a0 = bp1[c], a1 = bp1[c];
        for (int n = 0; n < 64; ++n) {
            float wv = Wp1[n * 64 + c];
            a0 += scA[ob * 64 + n] * wv;
            a1 += scA[(ob + 16) * 64 + n] * wv;
        }
        scB[ob * 64 + c] = eluf(a0);
        scB[(ob + 16) * 64 + c] = eluf(a1);
    }
    __syncthreads();
    if (t < 256) {
        int o = t >> 3, k = t & 7;
        float a = bp2[k];
        for (int n = 0; n < 64; ++n) a += scB[o * 64 + n] * Wp2[n * 8 + k];
        float m = a;
        m = fmaxf(m, __shfl_xor(m, 1));
        m = fmaxf(m, __shfl_xor(m, 2));
        m = fmaxf(m, __shfl_xor(m, 4));
        float e = expf(a - m);
        float sden = e;
        sden += __shfl_xor(sden, 1); sden += __shfl_xor(sden, 2); sden += __shfl_xor(sden, 4);
        float logpi = a - m - logf(sden);
        float v = logpi + lps[o * 8 + k];
        float mv = v;
        mv = fmaxf(mv, __shfl_xor(mv, 1));
        mv = fmaxf(mv, __shfl_xor(mv, 2));
        mv = fmaxf(mv, __shfl_xor(mv, 4));
        float ee = expf(v - mv);
        float ss = ee;
        ss += __shfl_xor(ss, 1); ss += __shfl_xor(ss, 2); ss += __shfl_xor(ss, 4);
        if (k == 0) lses[o] = mv + logf(ss);
    }
    __syncthreads();
    if (t == 0) {
        float p = 0.0f;
        #pragma unroll
        for (int o = 0; o < ROWS; ++o) p += lses[o];
        partials[q] = p;
    }
}

__global__ void reduce_partials(const float* __restrict__ partials, float* __restrict__ out)
{
    __shared__ double red[256];
    int t = threadIdx.x;
    double s = 0.0;
    for (int i = t; i < NBLK; i += 256) s += (double)partials[i];
    red[t] = s;
    __syncthreads();
    for (int w = 128; w > 0; w >>= 1) {
        if (t < w) red[t] += red[t + w];
        __syncthreads();
    }
    if (t == 0) out[0] = (float)(-red[0] / (double)B_TOT);
}

extern "C" void kernel_launch(void* const* d_in, const int* in_sizes, int n_in,
                              void* d_out, int out_size, void* d_ws, size_t ws_size,
                              hipStream_t stream)
{
    const float* x   = (const float*)d_in[0];
    const float* y   = (const float*)d_in[1];
    const float* W1  = (const float*)d_in[2];
    const float* b1  = (const float*)d_in[3];
    const float* W2  = (const float*)d_in[4];
    const float* b2  = (const float*)d_in[5];
    const float* Wp1 = (const float*)d_in[6];
    const float* bp1 = (const float*)d_in[7];
    const float* Wp2 = (const float*)d_in[8];
    const float* bp2 = (const float*)d_in[9];

    char* ws = (char*)d_ws;
    unsigned short* W2P_hi = (unsigned short*)(ws + WS_W2HI);
    unsigned short* W2P_lo = (unsigned short*)(ws + WS_W2LO);
    unsigned short* W1P_hi = (unsigned short*)(ws + WS_W1HI);
    unsigned short* W1P_lo = (unsigned short*)(ws + WS_W1LO);
    float* partials        = (float*)(ws + WS_PART);

    pack_split<<<dim3(16, 16), 256, 0, stream>>>(W2, W2P_hi, W2P_lo, 1024);
    pack_split<<<dim3(1, 16), 256, 0, stream>>>(W1, W1P_hi, W1P_lo, 64);
    fused_mdn<<<NBLK, THREADS, 0, stream>>>(x, y, W1P_hi, W1P_lo, b1, W2P_hi, W2P_lo, b2,
                                            Wp1, bp1, Wp2, bp2, partials);
    reduce_partials<<<1, 256, 0, stream>>>(partials, (float*)d_out);
}